// Round 4
// baseline (2486.288 us; speedup 1.0000x reference)
//
// Persistent cooperative LSTM kernel for MI355X (gfx950) — round 4.
//  - 256 blocks x 256 threads, 1 block/CU. Block b owns hidden units 4b..4b+3
//    of BOTH layers. Weights live in VGPRs as bf16 MFMA B-fragments.
//  - R4 change vs R3 (which was MALL-bound: sc1 loads forced every block to
//    ingest all 128KB of h from L3 every pass = 32MB/pass aggregate + 900cyc
//    latency on every wait-all):
//    UNIQUE PER-PHASE BUFFERS: each of the 226 h/relu states gets its own
//    128KB slot (29.6MB of ws). No address is ever re-written within a launch,
//    so consumers use PLAIN CACHED loads (L1+L2 absorb the 32-CU broadcast;
//    MALL sees 1MB/pass instead of 32MB). Cross-launch staleness (graph replay
//    reuses addresses) is cleared by ONE __threadfence() at kernel entry.
//    Slot order is reversed in memory so stream-prefetch direction points at
//    already-final slots. Stores remain write-through (sc0 sc1) to MALL;
//    barrier release remains vmcnt(0) drain; no other fences.
//  - Falls back to the R3 path (2-cycle buffers + sc1 loads) if ws too small.
#include <hip/hip_runtime.h>

typedef __attribute__((ext_vector_type(8))) short short8;
typedef __attribute__((ext_vector_type(4))) int int4_;
typedef __attribute__((ext_vector_type(4))) float float4_;

#define AGENT __HIP_MEMORY_SCOPE_AGENT

__device__ __forceinline__ unsigned short f2bf(float f) {
    unsigned u = __builtin_bit_cast(unsigned, f);
    u = (u + 0x7FFFu + ((u >> 16) & 1u)) >> 16;
    return (unsigned short)u;
}
__device__ __forceinline__ float bf2f(unsigned short h) {
    unsigned u = ((unsigned)h) << 16;
    return __builtin_bit_cast(float, u);
}
__device__ __forceinline__ float sigm(float x) { return 1.0f / (1.0f + __expf(-x)); }
__device__ __forceinline__ float tanhf_(float x) {
    x = fminf(fmaxf(x, -15.0f), 15.0f);
    float e = __expf(2.0f * x);
    return (e - 1.0f) / (e + 1.0f);
}

// coherent 8B store (write-through to coherence point)
__device__ __forceinline__ void st8_coh(unsigned short* p, unsigned long long v) {
    asm volatile("global_store_dwordx2 %0, %1, off sc0 sc1" :: "v"(p), "v"(v) : "memory");
}

// ---- grid barrier: NO fences. Release = vmcnt drain (sc-stores commit at
// coherence point); acquire = consumers' data is coherent by construction. ----
__device__ __forceinline__ void gbar(unsigned* bar, unsigned target, int grpId) {
    asm volatile("s_waitcnt vmcnt(0)" ::: "memory");
    __syncthreads();
    if (threadIdx.x == 0) {
        unsigned old = __hip_atomic_fetch_add(bar + 256 + grpId * 16, 1u, __ATOMIC_RELAXED, AGENT);
        if ((old & 15u) == 15u) {
            unsigned old2 = __hip_atomic_fetch_add(bar + 512, 1u, __ATOMIC_RELAXED, AGENT);
            if ((old2 & 15u) == 15u) {
#pragma unroll
                for (int g = 0; g < 16; g++)
                    __hip_atomic_store(bar + g * 16, target, __ATOMIC_RELAXED, AGENT);
            }
        }
        while (__hip_atomic_load(bar + grpId * 16, __ATOMIC_RELAXED, AGENT) < target)
            __builtin_amdgcn_s_sleep(2);
    }
    __syncthreads();
}

__device__ __forceinline__ void zero4(float4_ (&a)[4]) {
    float4_ z;
    z[0] = 0.f; z[1] = 0.f; z[2] = 0.f; z[3] = 0.f;
#pragma unroll
    for (int i = 0; i < 4; i++) a[i] = z;
}

#define LD_COH(dst, base, OFF) \
    asm volatile("global_load_dwordx4 %0, %1, off offset:" #OFF " sc0 sc1" \
                 : "=v"(dst) : "v"(base))

// A row-major [64][1024] bf16. A-frag: m = lane&15 (+16*mt), k = quad*8+j.
// B[k][n]: n = lane&15, k = quad*8+j.  C[m][n]: n = lane&15, m = quad*4+reg.
// COH=true: R3 path (sc1 loads + explicit drains). COH=false: plain cached
// loads, compiler-scheduled (fresh-by-construction addresses).
template<bool COH>
__device__ __forceinline__ void mm_pass(const unsigned short* __restrict__ A,
                                        int q, int lane,
                                        const short8 (&bf)[8], float4_ (&acc)[4]) {
    const int r0 = lane & 15;
    const int kq = (q << 8) + ((lane >> 4) << 3);
    if constexpr (COH) {
#pragma unroll
        for (int h = 0; h < 2; h++) {
            int4_ f[2][8];
#pragma unroll
            for (int mt2 = 0; mt2 < 2; mt2++) {
                const unsigned short* Ar = A + ((h * 2 + mt2) * 16 + r0) * 1024 + kq;
                LD_COH(f[mt2][0], Ar, 0);
                LD_COH(f[mt2][1], Ar, 64);
                LD_COH(f[mt2][2], Ar, 128);
                LD_COH(f[mt2][3], Ar, 192);
                LD_COH(f[mt2][4], Ar, 256);
                LD_COH(f[mt2][5], Ar, 320);
                LD_COH(f[mt2][6], Ar, 384);
                LD_COH(f[mt2][7], Ar, 448);
            }
            asm volatile("s_waitcnt vmcnt(0)"
                         : "+v"(f[0][0]), "+v"(f[0][1]), "+v"(f[0][2]), "+v"(f[0][3]),
                           "+v"(f[0][4]), "+v"(f[0][5]), "+v"(f[0][6]), "+v"(f[0][7]),
                           "+v"(f[1][0]), "+v"(f[1][1]), "+v"(f[1][2]), "+v"(f[1][3]),
                           "+v"(f[1][4]), "+v"(f[1][5]), "+v"(f[1][6]), "+v"(f[1][7]));
#pragma unroll
            for (int mt2 = 0; mt2 < 2; mt2++)
#pragma unroll
                for (int s = 0; s < 8; s++)
                    acc[h * 2 + mt2] = __builtin_amdgcn_mfma_f32_16x16x32_bf16(
                        __builtin_bit_cast(short8, f[mt2][s]), bf[s], acc[h * 2 + mt2], 0, 0, 0);
        }
    } else {
#pragma unroll
        for (int mt = 0; mt < 4; mt++) {
            const unsigned short* Ar = A + (mt * 16 + r0) * 1024 + kq;
            short8 a[8];
#pragma unroll
            for (int s = 0; s < 8; s++) a[s] = *(const short8*)(Ar + s * 32);
#pragma unroll
            for (int s = 0; s < 8; s++)
                acc[mt] = __builtin_amdgcn_mfma_f32_16x16x32_bf16(a[s], bf[s], acc[mt], 0, 0, 0);
        }
    }
}

__device__ __forceinline__ void write_parts(float* gp, int q, int lane, float4_ (&acc)[4]) {
    const int col = lane & 15;
    const int rbase = (lane >> 4) * 4;
#pragma unroll
    for (int mt = 0; mt < 4; mt++)
#pragma unroll
        for (int r = 0; r < 4; r++)
            gp[(q * 64 + mt * 16 + rbase + r) * 17 + col] = acc[mt][r];
}

__device__ __forceinline__ float gsum(const float* gp, int b, int c) {
    return gp[(0 * 64 + b) * 17 + c] + gp[(1 * 64 + b) * 17 + c] +
           gp[(2 * 64 + b) * 17 + c] + gp[(3 * 64 + b) * 17 + c];
}

__device__ __forceinline__ short8 packrow(const float* __restrict__ p) {
    short8 r;
#pragma unroll
    for (int j = 0; j < 8; j++) r[j] = (short)f2bf(p[j]);
    return r;
}

// State sequence index s: s=0 is the zero state; L0/L1 step writes s=t+1
// reading s=t (encoder t in [0,64), decoder continues s=65..96).
template<bool UNIQ>
__global__ void __launch_bounds__(256, 1)
lstm_core(const float* __restrict__ x, const float* __restrict__ lastp,
          const float* __restrict__ Wih0, const float* __restrict__ Whh0,
          const float* __restrict__ bih0, const float* __restrict__ bhh0,
          const float* __restrict__ Wih1, const float* __restrict__ Whh1,
          const float* __restrict__ bih1, const float* __restrict__ bhh1,
          const float* __restrict__ W1, const float* __restrict__ b1,
          const float* __restrict__ W2, const float* __restrict__ b2,
          float* __restrict__ out, unsigned char* __restrict__ wsb)
{
    constexpr bool COH = !UNIQ;
    const int tid = threadIdx.x;
    const int blk = blockIdx.x;
    const int lane = tid & 63;
    const int q = tid >> 6;          // wave id = K quarter
    const int grpId = blk & 15;
    const int eb = tid >> 2;         // epilogue: batch row
    const int eu = tid & 3;          // epilogue: unit-within-block
    const int D_ = blk * 4 + eu;     // global hidden unit / fc dim

    if constexpr (UNIQ) __threadfence();  // once: clear cross-launch L1/L2 residue

    unsigned* bar = (unsigned*)wsb;
    // Legacy (COH) 2-cycle buffers:
    unsigned short* h0buf2[2] = {(unsigned short*)(wsb + 8192),
                                 (unsigned short*)(wsb + 8192 + 131072)};
    unsigned short* h1buf2[2] = {(unsigned short*)(wsb + 270336),
                                 (unsigned short*)(wsb + 270336 + 131072)};
    unsigned short* relub2 = (unsigned short*)(wsb + 532480);
    // UNIQ slot regions (reversed order within each region):
    unsigned short* H0B = (unsigned short*)(wsb + 8192);            // 97 slots
    unsigned short* H1B = H0B + 97 * 65536;                          // 97 slots
    unsigned short* RLB = H1B + 97 * 65536;                          // 32 slots

    auto h0ptr = [&](int s) -> unsigned short* {
        if constexpr (UNIQ) return H0B + (96 - s) * 65536;
        else return h0buf2[(s + 1) & 1];
    };
    auto h1ptr = [&](int s) -> unsigned short* {
        if constexpr (UNIQ) return H1B + (96 - s) * 65536;
        else return h1buf2[(s + 1) & 1];
    };
    auto reluptr = [&](int t) -> unsigned short* {
        if constexpr (UNIQ) return RLB + (31 - t) * 65536;
        else return relub2 + t * 65536;
    };

    __shared__ float gparts[4 * 64 * 17];
    __shared__ float xlds[64 * 21];
    __shared__ float wih0l[16 * 20];
    __shared__ unsigned long long hstage_u64[64];
    unsigned short* hstage = (unsigned short*)hstage_u64;

    // ---- barrier area init (block 0) ----
    if (blk == 0 && tid == 0) {
        for (int g = 0; g < 16; g++) {
            __hip_atomic_store(bar + g * 16, 0u, __ATOMIC_RELAXED, AGENT);
            __hip_atomic_store(bar + 256 + g * 16, 0u, __ATOMIC_RELAXED, AGENT);
        }
        __hip_atomic_store(bar + 512, 0u, __ATOMIC_RELAXED, AGENT);
        __hip_atomic_store(bar + 544, 0x1357BDFu, __ATOMIC_RELEASE, AGENT);
    }

    // ---- per-lane B-fragment preload (bf16, RNE) ----
    const int n_ = lane & 15;
    const int gq_ = n_ >> 2, uu_ = n_ & 3;
    const int growL = gq_ * 1024 + blk * 4 + uu_;   // gate row for this col
    const int kq = (q << 8) + ((lane >> 4) << 3);

    short8 whh0f[8], wih1f[8], whh1f[8], wfusedf[8], wfcf[8];
#pragma unroll
    for (int s = 0; s < 8; s++) {
        const int k = kq + s * 32;
        whh0f[s] = packrow(Whh0 + growL * 1024 + k);
        wih1f[s] = packrow(Wih1 + growL * 1024 + k);
        whh1f[s] = packrow(Whh1 + growL * 1024 + k);
        { // Wfused[row][k] = sum_m Wih0[row][m] * W2[m][k]
            float a8[8] = {0.f, 0.f, 0.f, 0.f, 0.f, 0.f, 0.f, 0.f};
            for (int m = 0; m < 20; m++) {
                float wv = Wih0[growL * 20 + m];
                const float* w2p = W2 + m * 1024 + k;
#pragma unroll
                for (int j = 0; j < 8; j++) a8[j] += wv * w2p[j];
            }
            short8 r;
#pragma unroll
            for (int j = 0; j < 8; j++) r[j] = (short)f2bf(a8[j]);
            wfusedf[s] = r;
        }
        { // fc B: cols 0-3 = W1h rows, cols 4-7 = Wskip rows, 8-15 = 0
            short8 r;
            if (n_ < 4) {
                r = packrow(W1 + (blk * 4 + n_) * 1040 + k);
            } else if (n_ < 8) {
                const int D = blk * 4 + (n_ - 4);
                float a8[8] = {0.f, 0.f, 0.f, 0.f, 0.f, 0.f, 0.f, 0.f};
                for (int g2 = 0; g2 < 16; g2++) {
                    const int m = 5 * (g2 >> 2) + (g2 & 3);
                    float wv = W1[D * 1040 + 1024 + g2] * 0.01f;
                    const float* w2p = W2 + m * 1024 + k;
#pragma unroll
                    for (int j = 0; j < 8; j++) a8[j] += wv * w2p[j];
                }
#pragma unroll
                for (int j = 0; j < 8; j++) r[j] = (short)f2bf(a8[j]);
            } else {
#pragma unroll
                for (int j = 0; j < 8; j++) r[j] = 0;
            }
            wfcf[s] = r;
        }
    }

    // ---- per-thread constants (epilogue mapping: eb = tid>>2, eu = tid&3) ----
    float bias0g[4], bias1g[4], cgv[4];
#pragma unroll
    for (int g = 0; g < 4; g++) {
        const int row = g * 1024 + D_;
        bias0g[g] = bih0[row] + bhh0[row];
        bias1g[g] = bih1[row] + bhh1[row];
        float s = 0.f;
        for (int m = 0; m < 20; m++) s += Wih0[row * 20 + m] * b2[m];
        cgv[g] = s;
    }
    const float fcb = b1[D_];
    float cbv = 0.f, ustate = 0.f;
    for (int g2 = 0; g2 < 16; g2++) {
        const float w1v = W1[D_ * 1040 + 1024 + g2];
        cbv += b2[5 * (g2 >> 2) + (g2 & 3)] * w1v * 0.01f;
        ustate += lastp[eb * 16 + g2] * w1v;   // u(0) = lp0 @ W1lp^T
    }
    float c0v = 0.f, c1v = 0.f;

    if (tid < 16) { // Wih0 rows for x-path (fp32, exact)
        const int row = (tid >> 2) * 1024 + blk * 4 + (tid & 3);
        for (int m = 0; m < 20; m++) wih0l[tid * 20 + m] = Wih0[row * 20 + m];
    }
    // zero initial h state (s = 0); coherent stores
    if (tid < 64) {
        st8_coh(h0ptr(0) + tid * 1024 + blk * 4, 0ull);
        st8_coh(h1ptr(0) + tid * 1024 + blk * 4, 0ull);
    }

    if (tid == 0) {
        while (__hip_atomic_load(bar + 544, __ATOMIC_RELAXED, AGENT) != 0x1357BDFu)
            __builtin_amdgcn_s_sleep(2);
    }
    unsigned tgt = 1;
    gbar(bar, tgt++, grpId);

    // ---- phase lambdas ----
    auto stage_and_store = [&](unsigned short* dst, unsigned short val) {
        hstage[tid] = val;           // hstage[eb*4+eu] == hstage[tid]
        __syncthreads();
        if (tid < 64)
            st8_coh(dst + tid * 1024 + blk * 4, hstage_u64[tid]);
    };

    auto do_l0 = [&](const unsigned short* h0prev, unsigned short* h0dst,
                     const unsigned short* reluprev, int xt) {
        float4_ acc[4];
        zero4(acc);
        mm_pass<COH>(h0prev, q, lane, whh0f, acc);
        if (reluprev) mm_pass<COH>(reluprev, q, lane, wfusedf, acc);
        if (xt >= 0) {
            for (int i = tid; i < 1280; i += 256) {
                const int bb = i / 20, mm = i - bb * 20;
                xlds[bb * 21 + mm] = x[bb * 1280 + xt * 20 + mm];
            }
        }
        write_parts(gparts, q, lane, acc);
        __syncthreads();
        float gv[4];
#pragma unroll
        for (int g = 0; g < 4; g++) gv[g] = gsum(gparts, eb, g * 4 + eu) + bias0g[g];
        if (xt >= 0) {
#pragma unroll
            for (int g = 0; g < 4; g++) {
                float s = 0.f;
                const float* wr = &wih0l[(g * 4 + eu) * 20];
                const float* xr = &xlds[eb * 21];
                for (int m = 0; m < 20; m++) s += xr[m] * wr[m];
                gv[g] += s;
            }
        } else {
#pragma unroll
            for (int g = 0; g < 4; g++) gv[g] += cgv[g];
        }
        const float iv = sigm(gv[0]), fv = sigm(gv[1]);
        const float gt = tanhf_(gv[2]), ov = sigm(gv[3]);
        c0v = fv * c0v + iv * gt;
        stage_and_store(h0dst, f2bf(ov * tanhf_(c0v)));
    };

    auto do_l1 = [&](const unsigned short* h0cur, const unsigned short* h1prev,
                     unsigned short* h1dst) {
        float4_ acc[4];
        zero4(acc);
        mm_pass<COH>(h0cur, q, lane, wih1f, acc);
        mm_pass<COH>(h1prev, q, lane, whh1f, acc);
        write_parts(gparts, q, lane, acc);
        __syncthreads();
        float gv[4];
#pragma unroll
        for (int g = 0; g < 4; g++) gv[g] = gsum(gparts, eb, g * 4 + eu) + bias1g[g];
        const float iv = sigm(gv[0]), fv = sigm(gv[1]);
        const float gt = tanhf_(gv[2]), ov = sigm(gv[3]);
        c1v = fv * c1v + iv * gt;
        stage_and_store(h1dst, f2bf(ov * tanhf_(c1v)));
    };

    auto do_fc = [&](int t, const unsigned short* h1cur, const unsigned short* reluprev) {
        float4_ acc1[4], acc2[4];
        zero4(acc1);
        zero4(acc2);
        mm_pass<COH>(h1cur, q, lane, wfcf, acc1);              // cols 0-3: W1h@h1
        if (reluprev) mm_pass<COH>(reluprev, q, lane, wfcf, acc2); // cols 4-7: Wskip@relu
        {
            const int col = lane & 15;
            const int rbase = (lane >> 4) * 4;
            if (col < 8) {
#pragma unroll
                for (int mt = 0; mt < 4; mt++)
#pragma unroll
                    for (int r = 0; r < 4; r++) {
                        const float v = (col < 4) ? acc1[mt][r] : acc2[mt][r];
                        gparts[(q * 64 + mt * 16 + rbase + r) * 17 + col] = v;
                    }
            }
        }
        __syncthreads();
        const float s1 = gsum(gparts, eb, eu);
        if (t > 0) ustate += gsum(gparts, eb, 4 + eu) + cbv;
        const float rv = fmaxf(s1 + ustate + fcb, 0.f);
        stage_and_store(reluptr(t), f2bf(rv));
    };

    // ---- encoder: 64 steps x {L0, barrier, L1} (post-L1 barrier elided) ----
    for (int t = 0; t < 64; t++) {
        do_l0(h0ptr(t), h0ptr(t + 1), nullptr, t);
        gbar(bar, tgt++, grpId);
        do_l1(h0ptr(t + 1), h1ptr(t), h1ptr(t + 1));
    }
    // ---- decoder: 32 steps x {L0, b, L1, b, FC, b} ----
    for (int t = 0; t < 32; t++) {
        const unsigned short* rp = (t > 0) ? reluptr(t - 1) : nullptr;
        do_l0(h0ptr(64 + t), h0ptr(65 + t), rp, (t == 0) ? 63 : -1);
        gbar(bar, tgt++, grpId);
        do_l1(h0ptr(65 + t), h1ptr(64 + t), h1ptr(65 + t));
        gbar(bar, tgt++, grpId);
        do_fc(t, h1ptr(65 + t), rp);
        gbar(bar, tgt++, grpId);
    }

    // ---- final: pred[t] = relu[t] @ W2^T + b2 -> out[b][t][m] ----
    {
        const int pj = tid >> 5;   // 8 (t,b) pairs per block
        const int m = tid & 31;
        if (m < 20) {
            const int pidx = blk * 8 + pj;
            const int tt = pidx >> 6, bb = pidx & 63;
            const unsigned short* rr = reluptr(tt) + bb * 1024;
            const float* w = W2 + m * 1024;
            float acc = 0.f;
            for (int k2 = 0; k2 < 1024; k2 += 8) {
                short8 r8 = *(const short8*)(rr + k2);
#pragma unroll
                for (int j = 0; j < 8; j++)
                    acc += bf2f((unsigned short)r8[j]) * w[k2 + j];
            }
            out[bb * 640 + tt * 20 + m] = acc + b2[m];
        }
    }
}

extern "C" void kernel_launch(void* const* d_in, const int* in_sizes, int n_in,
                              void* d_out, int out_size, void* d_ws, size_t ws_size,
                              hipStream_t stream) {
    (void)in_sizes; (void)n_in; (void)out_size;
    const float* x     = (const float*)d_in[0];
    const float* lastp = (const float*)d_in[1];
    const float* Wih0  = (const float*)d_in[2];
    const float* Whh0  = (const float*)d_in[3];
    const float* bih0  = (const float*)d_in[4];
    const float* bhh0  = (const float*)d_in[5];
    const float* Wih1  = (const float*)d_in[6];
    const float* Whh1  = (const float*)d_in[7];
    const float* bih1  = (const float*)d_in[8];
    const float* bhh1  = (const float*)d_in[9];
    const float* W1    = (const float*)d_in[10];
    const float* b1    = (const float*)d_in[11];
    const float* W2    = (const float*)d_in[12];
    const float* b2    = (const float*)d_in[13];
    float* out = (float*)d_out;
    unsigned char* ws = (unsigned char*)d_ws;

    void* args[] = {&x, &lastp, &Wih0, &Whh0, &bih0, &bhh0, &Wih1, &Whh1,
                    &bih1, &bhh1, &W1, &b1, &W2, &b2, &out, &ws};

    const size_t need = 8192ull + 226ull * 131072ull;   // ~29.6 MB
    const void* fn = (ws_size >= need) ? (const void*)&lstm_core<true>
                                       : (const void*)&lstm_core<false>;
    hipError_t err = hipLaunchCooperativeKernel(fn, dim3(256), dim3(256), args, 0, stream);
    if (err != hipSuccess) {
        if (ws_size >= need)
            hipLaunchKernelGGL(lstm_core<true>, dim3(256), dim3(256), 0, stream,
                               x, lastp, Wih0, Whh0, bih0, bhh0, Wih1, Whh1,
                               bih1, bhh1, W1, b1, W2, b2, out, ws);
        else
            hipLaunchKernelGGL(lstm_core<false>, dim3(256), dim3(256), 0, stream,
                               x, lastp, Wih0, Whh0, bih0, bhh0, Wih1, Whh1,
                               bih1, bhh1, W1, b1, W2, b2, out, ws);
    }
}